// Round 2
// baseline (694.992 us; speedup 1.0000x reference)
//
#include <hip/hip_runtime.h>

// GCN 2-layer, N=100k, E=3.2M, IN=2, HID=64, OUT=1. All tensors float32.
// Algebraic restructure: norm = dinv[r]*dinv[c] and both matmuls are linear,
// so edge scatters move only 2 floats (layer1) / 1 float (layer2) per edge
// instead of the 64-dim hidden vector. h1 is never materialized.

#define BLOCK 256

__global__ void k_init(int* __restrict__ deg, float2* __restrict__ agg,
                       float* __restrict__ o, int n) {
    int i = blockIdx.x * blockDim.x + threadIdx.x;
    if (i < n) {
        deg[i] = 1;              // self-loop
        agg[i] = make_float2(0.f, 0.f);
        o[i] = 0.f;
    }
}

__global__ void k_deg(const int* __restrict__ col, int* __restrict__ deg, int E) {
    int e = blockIdx.x * blockDim.x + threadIdx.x;
    if (e < E) atomicAdd(&deg[col[e]], 1);
}

__global__ void k_dinv(const int* __restrict__ deg, float* __restrict__ dinv, int n) {
    int i = blockIdx.x * blockDim.x + threadIdx.x;
    if (i < n) dinv[i] = rsqrtf((float)deg[i]);   // deg >= 1 always (self-loop)
}

// layer-1 scatter: agg[c] += dinv[r] * x[r]  (2 floats per edge)
__global__ void k_scatter1(const int* __restrict__ row, const int* __restrict__ col,
                           const float2* __restrict__ x,
                           const float* __restrict__ dinv,
                           float* __restrict__ agg, int E) {
    int e = blockIdx.x * blockDim.x + threadIdx.x;
    if (e < E) {
        int r = row[e], c = col[e];
        float dr = dinv[r];
        float2 xv = x[r];
        atomicAdd(&agg[2 * c],     dr * xv.x);
        atomicAdd(&agg[2 * c + 1], dr * xv.y);
    }
}

// per-node: a = dinv*(agg + dinv*x_self), h1 = relu(a@W1 + b1), t = dinv*(h1@W2)
__global__ void k_node(const float2* __restrict__ x,
                       const float* __restrict__ dinv,
                       const float2* __restrict__ agg,
                       const float* __restrict__ W1,   // [2,64] row-major
                       const float* __restrict__ b1,   // [64]
                       const float* __restrict__ W2,   // [64,1]
                       float* __restrict__ t, int n) {
    __shared__ float sW1a[64], sW1b[64], sb1[64], sW2[64];
    int tid = threadIdx.x;
    if (tid < 64) {
        sW1a[tid] = W1[tid];
        sW1b[tid] = W1[64 + tid];
        sb1[tid]  = b1[tid];
        sW2[tid]  = W2[tid];
    }
    __syncthreads();
    int i = blockIdx.x * blockDim.x + tid;
    if (i < n) {
        float di = dinv[i];
        float2 av = agg[i];
        float2 xv = x[i];
        float a0 = di * (av.x + di * xv.x);
        float a1 = di * (av.y + di * xv.y);
        float acc = 0.f;
#pragma unroll
        for (int h = 0; h < 64; ++h) {
            float v = fmaf(a0, sW1a[h], fmaf(a1, sW1b[h], sb1[h]));
            v = fmaxf(v, 0.f);
            acc = fmaf(v, sW2[h], acc);
        }
        t[i] = di * acc;
    }
}

// layer-2 scatter: o[c] += t[r]  (1 float per edge)
__global__ void k_scatter2(const int* __restrict__ row, const int* __restrict__ col,
                           const float* __restrict__ t, float* __restrict__ o, int E) {
    int e = blockIdx.x * blockDim.x + threadIdx.x;
    if (e < E) atomicAdd(&o[col[e]], t[row[e]]);
}

__global__ void k_final(const float* __restrict__ dinv, const float* __restrict__ t,
                        const float* __restrict__ o,
                        const float* __restrict__ b2,
                        float* __restrict__ out, int n) {
    int i = blockIdx.x * blockDim.x + threadIdx.x;
    if (i < n) {
        out[i] = fmaf(dinv[i], o[i] + t[i], b2[0]);
    }
}

extern "C" void kernel_launch(void* const* d_in, const int* in_sizes, int n_in,
                              void* d_out, int out_size, void* d_ws, size_t ws_size,
                              hipStream_t stream) {
    const float* x  = (const float*)d_in[0];
    const int*   ei = (const int*)d_in[1];
    const float* W1 = (const float*)d_in[2];
    const float* b1 = (const float*)d_in[3];
    const float* W2 = (const float*)d_in[4];
    const float* b2 = (const float*)d_in[5];
    float* out = (float*)d_out;

    const int n = in_sizes[0] / 2;      // 100,000
    const int E = in_sizes[1] / 2;      // 3,200,000
    const int* row = ei;
    const int* col = ei + E;

    // workspace layout (4B elems): deg[n] | dinv[n] | agg[2n] | t[n] | o[n]
    char* ws = (char*)d_ws;
    int*   deg  = (int*)ws;
    float* dinv = (float*)(ws + (size_t)n * 4);
    float* agg  = (float*)(ws + (size_t)n * 8);
    float* t    = (float*)(ws + (size_t)n * 16);
    float* o    = (float*)(ws + (size_t)n * 20);

    int gn = (n + BLOCK - 1) / BLOCK;
    int ge = (E + BLOCK - 1) / BLOCK;

    k_init<<<gn, BLOCK, 0, stream>>>(deg, (float2*)agg, o, n);
    k_deg<<<ge, BLOCK, 0, stream>>>(col, deg, E);
    k_dinv<<<gn, BLOCK, 0, stream>>>(deg, dinv, n);
    k_scatter1<<<ge, BLOCK, 0, stream>>>(row, col, (const float2*)x, dinv, agg, E);
    k_node<<<gn, BLOCK, 0, stream>>>((const float2*)x, dinv, (const float2*)agg,
                                     W1, b1, W2, t, n);
    k_scatter2<<<ge, BLOCK, 0, stream>>>(row, col, t, o, E);
    k_final<<<gn, BLOCK, 0, stream>>>(dinv, t, o, b2, out, n);
}

// Round 3
// 248.947 us; speedup vs baseline: 2.7917x; 2.7917x over previous
//
#include <hip/hip_runtime.h>

// GCN 2-layer, N=100k, E=3.2M, IN=2, HID=64, OUT=1 (all float32).
// Round-2 showed device-scope atomics are the bottleneck (~20e9/s, 32B
// memory-side RMW each). This version has ZERO global atomics: destination
// nodes are partitioned into LDS-sized buckets; each (bucket, edge-chunk)
// workgroup accumulates with LDS atomics and writes a dense partial; merge
// kernels reduce the C partials per node. The 25.6MB edge list is L3-resident
// so the multi-pass re-scan is cheap.

#define BS1 8192    // nodes/bucket for layer-1 scatter (float2 -> 64KB LDS)
#define NB1 13      // ceil(100000/8192)
#define BS2 16384   // nodes/bucket for hist + layer-2 scatter (4B -> 64KB LDS)
#define NB2 7       // ceil(100000/16384)
#define TB  512
#define TN  256

// in-degree histogram of col, per-(bucket,chunk) partials
__global__ void k_hist(const int* __restrict__ col, int* __restrict__ pb,
                       int E, int C) {
    __shared__ int s[BS2];
    const int b = blockIdx.y, j = blockIdx.x;
    for (int i = threadIdx.x; i < BS2; i += TB) s[i] = 0;
    __syncthreads();
    const int base = b * BS2;
    const int g4 = E >> 2;
    const int4* col4 = (const int4*)col;
    const int g0 = (int)((long long)j * g4 / C);
    const int g1 = (int)((long long)(j + 1) * g4 / C);
    for (int g = g0 + threadIdx.x; g < g1; g += TB) {
        int4 c = col4[g];
        unsigned l;
        l = (unsigned)(c.x - base); if (l < BS2) atomicAdd(&s[l], 1);
        l = (unsigned)(c.y - base); if (l < BS2) atomicAdd(&s[l], 1);
        l = (unsigned)(c.z - base); if (l < BS2) atomicAdd(&s[l], 1);
        l = (unsigned)(c.w - base); if (l < BS2) atomicAdd(&s[l], 1);
    }
    if (j == 0) {  // scalar tail (E not multiple of 4)
        for (int e = (g4 << 2) + threadIdx.x; e < E; e += TB) {
            unsigned l = (unsigned)(col[e] - base);
            if (l < BS2) atomicAdd(&s[l], 1);
        }
    }
    __syncthreads();
    int4* dst = (int4*)(pb + ((size_t)(b * C + j) << 14));
    const int4* src = (const int4*)s;
    for (int i = threadIdx.x; i < (BS2 >> 2); i += TB) dst[i] = src[i];
}

// merge hist partials -> deg -> dinv; y[i] = dinv[i]*x[i]
__global__ void k_post1(const int* __restrict__ pb, const float2* __restrict__ x,
                        float* __restrict__ dinv, float2* __restrict__ y,
                        int n, int C) {
    int i = blockIdx.x * TN + threadIdx.x;
    if (i >= n) return;
    const int b = i >> 14, l = i & (BS2 - 1);
    int deg = 1;  // self-loop
    const int* p = pb + ((size_t)(b * C) << 14) + l;
    for (int j = 0; j < C; ++j) deg += p[(size_t)j << 14];
    float d = rsqrtf((float)deg);
    dinv[i] = d;
    float2 xv = x[i];
    y[i] = make_float2(d * xv.x, d * xv.y);
}

// layer-1 scatter: bucket-local LDS accumulate of y[row[e]] at col[e]
__global__ void k_s1(const int* __restrict__ row, const int* __restrict__ col,
                     const float2* __restrict__ y, float2* __restrict__ pb,
                     int E, int C) {
    __shared__ float2 s[BS1];
    const int b = blockIdx.y, j = blockIdx.x;
    for (int i = threadIdx.x; i < BS1; i += TB) s[i] = make_float2(0.f, 0.f);
    __syncthreads();
    const int base = b * BS1;
    const int g4 = E >> 2;
    const int4* col4 = (const int4*)col;
    const int4* row4 = (const int4*)row;
    const int g0 = (int)((long long)j * g4 / C);
    const int g1 = (int)((long long)(j + 1) * g4 / C);
    for (int g = g0 + threadIdx.x; g < g1; g += TB) {
        int4 c = col4[g];
        int4 r = row4[g];
        unsigned l;
        l = (unsigned)(c.x - base); if (l < BS1) { float2 v = y[r.x]; atomicAdd(&s[l].x, v.x); atomicAdd(&s[l].y, v.y); }
        l = (unsigned)(c.y - base); if (l < BS1) { float2 v = y[r.y]; atomicAdd(&s[l].x, v.x); atomicAdd(&s[l].y, v.y); }
        l = (unsigned)(c.z - base); if (l < BS1) { float2 v = y[r.z]; atomicAdd(&s[l].x, v.x); atomicAdd(&s[l].y, v.y); }
        l = (unsigned)(c.w - base); if (l < BS1) { float2 v = y[r.w]; atomicAdd(&s[l].x, v.x); atomicAdd(&s[l].y, v.y); }
    }
    if (j == 0) {
        for (int e = (g4 << 2) + threadIdx.x; e < E; e += TB) {
            unsigned l = (unsigned)(col[e] - base);
            if (l < BS1) { float2 v = y[row[e]]; atomicAdd(&s[l].x, v.x); atomicAdd(&s[l].y, v.y); }
        }
    }
    __syncthreads();
    float4* dst = (float4*)(pb + ((size_t)(b * C + j) << 13));
    const float4* src = (const float4*)s;
    for (int i = threadIdx.x; i < (BS1 >> 1); i += TB) dst[i] = src[i];
}

// merge layer-1 partials + per-node MLP: t[i] = dinv*(relu(a@W1+b1)@W2)
__global__ void k_post2(const float2* __restrict__ pb, const float2* __restrict__ y,
                        const float* __restrict__ dinv,
                        const float* __restrict__ W1, const float* __restrict__ b1,
                        const float* __restrict__ W2,
                        float* __restrict__ t, int n, int C) {
    __shared__ float sW1a[64], sW1b[64], sb1[64], sW2[64];
    if (threadIdx.x < 64) {
        sW1a[threadIdx.x] = W1[threadIdx.x];
        sW1b[threadIdx.x] = W1[64 + threadIdx.x];
        sb1[threadIdx.x]  = b1[threadIdx.x];
        sW2[threadIdx.x]  = W2[threadIdx.x];
    }
    __syncthreads();
    int i = blockIdx.x * TN + threadIdx.x;
    if (i >= n) return;
    const int b = i >> 13, l = i & (BS1 - 1);
    float gx = 0.f, gy = 0.f;
    const float2* p = pb + ((size_t)(b * C) << 13) + l;
    for (int j = 0; j < C; ++j) { float2 v = p[(size_t)j << 13]; gx += v.x; gy += v.y; }
    float d = dinv[i];
    float2 yv = y[i];
    float a0 = d * (gx + yv.x);
    float a1 = d * (gy + yv.y);
    float acc = 0.f;
#pragma unroll
    for (int h = 0; h < 64; ++h) {
        float v = fmaf(a0, sW1a[h], fmaf(a1, sW1b[h], sb1[h]));
        acc = fmaf(fmaxf(v, 0.f), sW2[h], acc);
    }
    t[i] = d * acc;
}

// layer-2 scatter: bucket-local LDS accumulate of t[row[e]] at col[e]
__global__ void k_s2(const int* __restrict__ row, const int* __restrict__ col,
                     const float* __restrict__ t, float* __restrict__ pb,
                     int E, int C) {
    __shared__ float s[BS2];
    const int b = blockIdx.y, j = blockIdx.x;
    for (int i = threadIdx.x; i < BS2; i += TB) s[i] = 0.f;
    __syncthreads();
    const int base = b * BS2;
    const int g4 = E >> 2;
    const int4* col4 = (const int4*)col;
    const int4* row4 = (const int4*)row;
    const int g0 = (int)((long long)j * g4 / C);
    const int g1 = (int)((long long)(j + 1) * g4 / C);
    for (int g = g0 + threadIdx.x; g < g1; g += TB) {
        int4 c = col4[g];
        int4 r = row4[g];
        unsigned l;
        l = (unsigned)(c.x - base); if (l < BS2) atomicAdd(&s[l], t[r.x]);
        l = (unsigned)(c.y - base); if (l < BS2) atomicAdd(&s[l], t[r.y]);
        l = (unsigned)(c.z - base); if (l < BS2) atomicAdd(&s[l], t[r.z]);
        l = (unsigned)(c.w - base); if (l < BS2) atomicAdd(&s[l], t[r.w]);
    }
    if (j == 0) {
        for (int e = (g4 << 2) + threadIdx.x; e < E; e += TB) {
            unsigned l = (unsigned)(col[e] - base);
            if (l < BS2) atomicAdd(&s[l], t[row[e]]);
        }
    }
    __syncthreads();
    float4* dst = (float4*)(pb + ((size_t)(b * C + j) << 14));
    const float4* src = (const float4*)s;
    for (int i = threadIdx.x; i < (BS2 >> 2); i += TB) dst[i] = src[i];
}

// merge layer-2 partials + epilogue
__global__ void k_post3(const float* __restrict__ pb, const float* __restrict__ t,
                        const float* __restrict__ dinv, const float* __restrict__ b2,
                        float* __restrict__ out, int n, int C) {
    int i = blockIdx.x * TN + threadIdx.x;
    if (i >= n) return;
    const int b = i >> 14, l = i & (BS2 - 1);
    float o = 0.f;
    const float* p = pb + ((size_t)(b * C) << 14) + l;
    for (int j = 0; j < C; ++j) o += p[(size_t)j << 14];
    out[i] = fmaf(dinv[i], o + t[i], b2[0]);
}

extern "C" void kernel_launch(void* const* d_in, const int* in_sizes, int n_in,
                              void* d_out, int out_size, void* d_ws, size_t ws_size,
                              hipStream_t stream) {
    const float* x  = (const float*)d_in[0];
    const int*   ei = (const int*)d_in[1];
    const float* W1 = (const float*)d_in[2];
    const float* b1 = (const float*)d_in[3];
    const float* W2 = (const float*)d_in[4];
    const float* b2 = (const float*)d_in[5];
    float* out = (float*)d_out;

    const int n = in_sizes[0] / 2;      // 100,000
    const int E = in_sizes[1] / 2;      // 3,200,000
    const int* row = ei;
    const int* col = ei + E;

    // ws: dinv[n] | y[n] (float2) | t[n] | (aligned) partial buffer
    char* ws = (char*)d_ws;
    size_t off = 0;
    float*  dinv = (float*)(ws + off);  off += (size_t)n * 4;
    float2* y    = (float2*)(ws + off); off += (size_t)n * 8;
    float*  t    = (float*)(ws + off);  off += (size_t)n * 4;
    off = (off + 255) & ~(size_t)255;
    void* pb = (void*)(ws + off);
    size_t pbBytes = ws_size > off ? ws_size - off : 0;

    int C1 = (int)(pbBytes / ((size_t)NB1 * BS1 * 8));  // float2 partials
    int C2 = (int)(pbBytes / ((size_t)NB2 * BS2 * 4));  // int/float partials
    if (C1 > 32) C1 = 32;  if (C1 < 1) C1 = 1;
    if (C2 > 32) C2 = 32;  if (C2 < 1) C2 = 1;

    const int gn = (n + TN - 1) / TN;

    k_hist <<<dim3(C2, NB2), TB, 0, stream>>>(col, (int*)pb, E, C2);
    k_post1<<<gn, TN, 0, stream>>>((const int*)pb, (const float2*)x, dinv, y, n, C2);
    k_s1   <<<dim3(C1, NB1), TB, 0, stream>>>(row, col, y, (float2*)pb, E, C1);
    k_post2<<<gn, TN, 0, stream>>>((const float2*)pb, y, dinv, W1, b1, W2, t, n, C1);
    k_s2   <<<dim3(C2, NB2), TB, 0, stream>>>(row, col, t, (float*)pb, E, C2);
    k_post3<<<gn, TN, 0, stream>>>((const float*)pb, t, dinv, b2, out, n, C2);
}

// Round 4
// 227.855 us; speedup vs baseline: 3.0501x; 1.0926x over previous
//
#include <hip/hip_runtime.h>

// GCN 2-layer, N=100k, E=3.2M, IN=2, HID=64, OUT=1 (all float32).
// Zero global atomics: destination nodes partitioned into LDS-sized buckets;
// each (bucket, edge-chunk) workgroup accumulates with LDS atomics and writes
// a dense partial; merge kernels reduce the C partials per node. Edge list
// (25.6MB) is L3-resident so the multi-pass rescan is cheap.
// R4: TB 512->1024 (32 waves/CU at 64KB LDS) + chunk caps 40/72 for a full
// residency round of ~512 blocks — scans were latency-bound at 25% occupancy.

#define BS1 8192    // nodes/bucket, layer-1 scatter (float2 -> 64KB LDS)
#define NB1 13      // ceil(100000/8192)
#define BS2 16384   // nodes/bucket, hist + layer-2 scatter (4B -> 64KB LDS)
#define NB2 7       // ceil(100000/16384)
#define TB  1024
#define TN  256

// in-degree histogram of col, per-(bucket,chunk) partials
__global__ void k_hist(const int* __restrict__ col, int* __restrict__ pb,
                       int E, int C) {
    __shared__ int s[BS2];
    const int b = blockIdx.y, j = blockIdx.x;
    for (int i = threadIdx.x; i < BS2; i += TB) s[i] = 0;
    __syncthreads();
    const int base = b * BS2;
    const int g4 = E >> 2;
    const int4* col4 = (const int4*)col;
    const int g0 = (int)((long long)j * g4 / C);
    const int g1 = (int)((long long)(j + 1) * g4 / C);
    for (int g = g0 + threadIdx.x; g < g1; g += TB) {
        int4 c = col4[g];
        unsigned l;
        l = (unsigned)(c.x - base); if (l < BS2) atomicAdd(&s[l], 1);
        l = (unsigned)(c.y - base); if (l < BS2) atomicAdd(&s[l], 1);
        l = (unsigned)(c.z - base); if (l < BS2) atomicAdd(&s[l], 1);
        l = (unsigned)(c.w - base); if (l < BS2) atomicAdd(&s[l], 1);
    }
    if (j == 0) {  // scalar tail (E not multiple of 4)
        for (int e = (g4 << 2) + threadIdx.x; e < E; e += TB) {
            unsigned l = (unsigned)(col[e] - base);
            if (l < BS2) atomicAdd(&s[l], 1);
        }
    }
    __syncthreads();
    int4* dst = (int4*)(pb + ((size_t)(b * C + j) << 14));
    const int4* src = (const int4*)s;
    for (int i = threadIdx.x; i < (BS2 >> 2); i += TB) dst[i] = src[i];
}

// merge hist partials -> deg -> dinv; y[i] = dinv[i]*x[i]
__global__ void k_post1(const int* __restrict__ pb, const float2* __restrict__ x,
                        float* __restrict__ dinv, float2* __restrict__ y,
                        int n, int C) {
    int i = blockIdx.x * TN + threadIdx.x;
    if (i >= n) return;
    const int b = i >> 14, l = i & (BS2 - 1);
    int deg = 1;  // self-loop
    const int* p = pb + ((size_t)(b * C) << 14) + l;
    for (int j = 0; j < C; ++j) deg += p[(size_t)j << 14];
    float d = rsqrtf((float)deg);
    dinv[i] = d;
    float2 xv = x[i];
    y[i] = make_float2(d * xv.x, d * xv.y);
}

// layer-1 scatter: bucket-local LDS accumulate of y[row[e]] at col[e]
__global__ void k_s1(const int* __restrict__ row, const int* __restrict__ col,
                     const float2* __restrict__ y, float2* __restrict__ pb,
                     int E, int C) {
    __shared__ float2 s[BS1];
    const int b = blockIdx.y, j = blockIdx.x;
    for (int i = threadIdx.x; i < BS1; i += TB) s[i] = make_float2(0.f, 0.f);
    __syncthreads();
    const int base = b * BS1;
    const int g4 = E >> 2;
    const int4* col4 = (const int4*)col;
    const int4* row4 = (const int4*)row;
    const int g0 = (int)((long long)j * g4 / C);
    const int g1 = (int)((long long)(j + 1) * g4 / C);
    for (int g = g0 + threadIdx.x; g < g1; g += TB) {
        int4 c = col4[g];
        int4 r = row4[g];
        unsigned l;
        l = (unsigned)(c.x - base); if (l < BS1) { float2 v = y[r.x]; atomicAdd(&s[l].x, v.x); atomicAdd(&s[l].y, v.y); }
        l = (unsigned)(c.y - base); if (l < BS1) { float2 v = y[r.y]; atomicAdd(&s[l].x, v.x); atomicAdd(&s[l].y, v.y); }
        l = (unsigned)(c.z - base); if (l < BS1) { float2 v = y[r.z]; atomicAdd(&s[l].x, v.x); atomicAdd(&s[l].y, v.y); }
        l = (unsigned)(c.w - base); if (l < BS1) { float2 v = y[r.w]; atomicAdd(&s[l].x, v.x); atomicAdd(&s[l].y, v.y); }
    }
    if (j == 0) {
        for (int e = (g4 << 2) + threadIdx.x; e < E; e += TB) {
            unsigned l = (unsigned)(col[e] - base);
            if (l < BS1) { float2 v = y[row[e]]; atomicAdd(&s[l].x, v.x); atomicAdd(&s[l].y, v.y); }
        }
    }
    __syncthreads();
    float4* dst = (float4*)(pb + ((size_t)(b * C + j) << 13));
    const float4* src = (const float4*)s;
    for (int i = threadIdx.x; i < (BS1 >> 1); i += TB) dst[i] = src[i];
}

// merge layer-1 partials + per-node MLP: t[i] = dinv*(relu(a@W1+b1)@W2)
__global__ void k_post2(const float2* __restrict__ pb, const float2* __restrict__ y,
                        const float* __restrict__ dinv,
                        const float* __restrict__ W1, const float* __restrict__ b1,
                        const float* __restrict__ W2,
                        float* __restrict__ t, int n, int C) {
    __shared__ float sW1a[64], sW1b[64], sb1[64], sW2[64];
    if (threadIdx.x < 64) {
        sW1a[threadIdx.x] = W1[threadIdx.x];
        sW1b[threadIdx.x] = W1[64 + threadIdx.x];
        sb1[threadIdx.x]  = b1[threadIdx.x];
        sW2[threadIdx.x]  = W2[threadIdx.x];
    }
    __syncthreads();
    int i = blockIdx.x * TN + threadIdx.x;
    if (i >= n) return;
    const int b = i >> 13, l = i & (BS1 - 1);
    float gx = 0.f, gy = 0.f;
    const float2* p = pb + ((size_t)(b * C) << 13) + l;
    for (int j = 0; j < C; ++j) { float2 v = p[(size_t)j << 13]; gx += v.x; gy += v.y; }
    float d = dinv[i];
    float2 yv = y[i];
    float a0 = d * (gx + yv.x);
    float a1 = d * (gy + yv.y);
    float acc = 0.f;
#pragma unroll
    for (int h = 0; h < 64; ++h) {
        float v = fmaf(a0, sW1a[h], fmaf(a1, sW1b[h], sb1[h]));
        acc = fmaf(fmaxf(v, 0.f), sW2[h], acc);
    }
    t[i] = d * acc;
}

// layer-2 scatter: bucket-local LDS accumulate of t[row[e]] at col[e]
__global__ void k_s2(const int* __restrict__ row, const int* __restrict__ col,
                     const float* __restrict__ t, float* __restrict__ pb,
                     int E, int C) {
    __shared__ float s[BS2];
    const int b = blockIdx.y, j = blockIdx.x;
    for (int i = threadIdx.x; i < BS2; i += TB) s[i] = 0.f;
    __syncthreads();
    const int base = b * BS2;
    const int g4 = E >> 2;
    const int4* col4 = (const int4*)col;
    const int4* row4 = (const int4*)row;
    const int g0 = (int)((long long)j * g4 / C);
    const int g1 = (int)((long long)(j + 1) * g4 / C);
    for (int g = g0 + threadIdx.x; g < g1; g += TB) {
        int4 c = col4[g];
        int4 r = row4[g];
        unsigned l;
        l = (unsigned)(c.x - base); if (l < BS2) atomicAdd(&s[l], t[r.x]);
        l = (unsigned)(c.y - base); if (l < BS2) atomicAdd(&s[l], t[r.y]);
        l = (unsigned)(c.z - base); if (l < BS2) atomicAdd(&s[l], t[r.z]);
        l = (unsigned)(c.w - base); if (l < BS2) atomicAdd(&s[l], t[r.w]);
    }
    if (j == 0) {
        for (int e = (g4 << 2) + threadIdx.x; e < E; e += TB) {
            unsigned l = (unsigned)(col[e] - base);
            if (l < BS2) atomicAdd(&s[l], t[row[e]]);
        }
    }
    __syncthreads();
    float4* dst = (float4*)(pb + ((size_t)(b * C + j) << 14));
    const float4* src = (const float4*)s;
    for (int i = threadIdx.x; i < (BS2 >> 2); i += TB) dst[i] = src[i];
}

// merge layer-2 partials + epilogue
__global__ void k_post3(const float* __restrict__ pb, const float* __restrict__ t,
                        const float* __restrict__ dinv, const float* __restrict__ b2,
                        float* __restrict__ out, int n, int C) {
    int i = blockIdx.x * TN + threadIdx.x;
    if (i >= n) return;
    const int b = i >> 14, l = i & (BS2 - 1);
    float o = 0.f;
    const float* p = pb + ((size_t)(b * C) << 14) + l;
    for (int j = 0; j < C; ++j) o += p[(size_t)j << 14];
    out[i] = fmaf(dinv[i], o + t[i], b2[0]);
}

extern "C" void kernel_launch(void* const* d_in, const int* in_sizes, int n_in,
                              void* d_out, int out_size, void* d_ws, size_t ws_size,
                              hipStream_t stream) {
    const float* x  = (const float*)d_in[0];
    const int*   ei = (const int*)d_in[1];
    const float* W1 = (const float*)d_in[2];
    const float* b1 = (const float*)d_in[3];
    const float* W2 = (const float*)d_in[4];
    const float* b2 = (const float*)d_in[5];
    float* out = (float*)d_out;

    const int n = in_sizes[0] / 2;      // 100,000
    const int E = in_sizes[1] / 2;      // 3,200,000
    const int* row = ei;
    const int* col = ei + E;

    // ws: dinv[n] | y[n] (float2) | t[n] | (aligned) partial buffer
    char* ws = (char*)d_ws;
    size_t off = 0;
    float*  dinv = (float*)(ws + off);  off += (size_t)n * 4;
    float2* y    = (float2*)(ws + off); off += (size_t)n * 8;
    float*  t    = (float*)(ws + off);  off += (size_t)n * 4;
    off = (off + 255) & ~(size_t)255;
    void* pb = (void*)(ws + off);
    size_t pbBytes = ws_size > off ? ws_size - off : 0;

    int C1 = (int)(pbBytes / ((size_t)NB1 * BS1 * 8));  // float2 partials
    int C2 = (int)(pbBytes / ((size_t)NB2 * BS2 * 4));  // int/float partials
    if (C1 > 40) C1 = 40;  if (C1 < 1) C1 = 1;   // 40*13=520 blocks ~ one full
    if (C2 > 72) C2 = 72;  if (C2 < 1) C2 = 1;   // residency round (2/CU)

    const int gn = (n + TN - 1) / TN;

    k_hist <<<dim3(C2, NB2), TB, 0, stream>>>(col, (int*)pb, E, C2);
    k_post1<<<gn, TN, 0, stream>>>((const int*)pb, (const float2*)x, dinv, y, n, C2);
    k_s1   <<<dim3(C1, NB1), TB, 0, stream>>>(row, col, y, (float2*)pb, E, C1);
    k_post2<<<gn, TN, 0, stream>>>((const float2*)pb, y, dinv, W1, b1, W2, t, n, C1);
    k_s2   <<<dim3(C2, NB2), TB, 0, stream>>>(row, col, t, (float*)pb, E, C2);
    k_post3<<<gn, TN, 0, stream>>>((const float*)pb, t, dinv, b2, out, n, C2);
}